// Round 10
// baseline (417.895 us; speedup 1.0000x reference)
//
#include <hip/hip_runtime.h>

// KrausRK4 via bf16 MFMA, r10: r9 frag-major structure, LDS cut to 4 buffers
// (32KB -> 5 blocks/CU) by making S=sand(Um,rho0) overwrite rho0's buffer via
// a split-phase barrier. 9 barrier phases. Wave-private quarter axpys.

typedef __attribute__((ext_vector_type(16))) float f32x16;
typedef __attribute__((ext_vector_type(8))) __bf16 bf16x8;

#define MATB 8192

__device__ __forceinline__ unsigned short bf16rne(float x) {
  unsigned u = __builtin_bit_cast(unsigned, x);
  return (unsigned short)((u + 0x7FFFu + ((u >> 16) & 1u)) >> 16);
}
__device__ __forceinline__ float bflo(unsigned u) {
  return __builtin_bit_cast(float, u << 16);
}
__device__ __forceinline__ float bfhi(unsigned u) {
  return __builtin_bit_cast(float, u & 0xFFFF0000u);
}
__device__ __forceinline__ unsigned pk2(float lo, float hi) {
  union { __bf16 h[2]; unsigned u; } r;
  r.h[0] = (__bf16)lo;
  r.h[1] = (__bf16)hi;
  return r.u;
}

union U4 { uint4 u; bf16x8 h; };

// Build step-s operand fragment (k = s*16 + lh*8 + i) from a C-tile.
__device__ __forceinline__ bf16x8 assemble(const f32x16& t, int b8, int lh) {
  unsigned u0 = pk2(t[b8 + 0], t[b8 + 1]);
  unsigned u1 = pk2(t[b8 + 2], t[b8 + 3]);
  unsigned w0 = pk2(t[b8 + 4], t[b8 + 5]);
  unsigned w1 = pk2(t[b8 + 6], t[b8 + 7]);
  unsigned z0 = lh ? u0 : w0;           // send what the partner needs
  unsigned z1 = lh ? u1 : w1;
  unsigned r0 = __shfl_xor(z0, 32);
  unsigned r1 = __shfl_xor(z1, 32);
  U4 r;
  r.u = make_uint4(lh ? r0 : u0, lh ? r1 : u1,
                   lh ? w0 : r0, lh ? w1 : r1);
  return r.h;
}

// ---------------- Um1 = U1 @ inv(Um), fp32 Gauss-Jordan, no pivot -----------
__global__ __launch_bounds__(256) void kraus_invert(
    const float* __restrict__ U1, const float* __restrict__ Um,
    float* __restrict__ Um1) {
  __shared__ float M[64][66];
  __shared__ float X[64][66];
  int tid = threadIdx.x;
#pragma unroll
  for (int it = 0; it < 16; ++it) {
    int idx = tid + 256 * it;
    int r = idx >> 6, c = idx & 63;
    M[r][c] = Um[idx];
    X[r][c] = (r == c) ? 1.0f : 0.0f;
  }
  __syncthreads();
  for (int k = 0; k < 64; ++k) {
    if (tid < 64) {
      float ip = 1.0f / M[k][k];
      M[k][tid] *= ip;
      X[k][tid] *= ip;
    }
    __syncthreads();
    int r = tid & 63, q = tid >> 6;
    float f = M[r][k];
    __syncthreads();
    if (r != k) {
#pragma unroll
      for (int cc = 0; cc < 16; ++cc) {
        int c = q * 16 + cc;
        M[r][c] -= f * M[k][c];
        X[r][c] -= f * X[k][c];
      }
    }
    __syncthreads();
  }
  for (int it = 0; it < 16; ++it) {
    int idx = tid + 256 * it;
    int i = idx >> 6, j = idx & 63;
    float s = 0.0f;
#pragma unroll 4
    for (int k = 0; k < 64; ++k) s += U1[i * 64 + k] * X[k][j];
    Um1[idx] = s;
  }
}

// ---------------- prepack: 15 operators -> bf16 fragment-major in ws --------
// op order: 0=U1 1=Um 2=Um1 3..6=Ls0 7..10=Lsmid 11..14=Ls1
__global__ __launch_bounds__(256) void kraus_prepack(
    const float* __restrict__ U1, const float* __restrict__ Um,
    const float* __restrict__ Ls0, const float* __restrict__ Lsmid,
    const float* __restrict__ Ls1, float* __restrict__ ws) {
  const float* Um1 = ws;
  unsigned short* dst = (unsigned short*)((char*)ws + 16384);
  int o = blockIdx.x;
  const float* s;
  if (o == 0) s = U1;
  else if (o == 1) s = Um;
  else if (o == 2) s = Um1;
  else if (o < 7) s = Ls0 + (o - 3) * 4096;
  else if (o < 11) s = Lsmid + (o - 7) * 4096;
  else s = Ls1 + (o - 11) * 4096;
  unsigned short* d = dst + o * 4096;
  int tid = threadIdx.x;
#pragma unroll
  for (int j = 0; j < 16; ++j) {
    int idx = tid + 256 * j;
    int f = idx >> 9, l = (idx >> 3) & 63, i = idx & 7;
    int t = f >> 2, ss = f & 3;
    int R = t * 32 + (l & 31);
    int C = ss * 16 + (l >> 5) * 8 + i;
    d[idx] = bf16rne(s[R * 64 + C]);
  }
}

// ---------------- main kernel: one block per batch item ---------------------
__global__ __launch_bounds__(256, 5) void kraus_main(
    const float* __restrict__ rho0g, const float* __restrict__ dtp,
    const char* __restrict__ gfrag, float* __restrict__ outg) {
  __shared__ __align__(16) char lds[4 * MATB];   // 32768 B -> 5 blocks/CU
  char* S1 = lds;              // rho0 -> S -> J3
  char* S2 = S1 + MATB;        // J0 -> P -> rho4
  char* S3 = S2 + MATB;        // T -> J2
  char* S4 = S3 + MATB;        // rho2 -> rho3

  const int tid = threadIdx.x;
  const int l = tid & 63, w = tid >> 6;
  const int ti = w >> 1, tj = w & 1;
  const int l31 = l & 31, lh = l >> 5;
  const int fragoff = l * 16;
  const int myslot = ((tj * 4 + 2 * ti) << 10) + fragoff;
  const float dt = dtp[0];
  const size_t b = blockIdx.x;

  auto GF = [&](int op, int blk) {
    return gfrag + op * 8192 + blk * 4096 + l * 16;
  };
  auto mmA = [&](f32x16& acc, const char* X, int a, const char* __restrict__ gQ) {
#pragma unroll
    for (int s = 0; s < 4; ++s) {
      bf16x8 aa = *(const bf16x8*)(X + ((a * 4 + s) << 10) + fragoff);
      bf16x8 bb = *(const bf16x8*)(gQ + s * 1024);
      acc = __builtin_amdgcn_mfma_f32_32x32x16_bf16(aa, bb, acc, 0, 0, 0);
    }
  };
  auto second = [&](f32x16& acc, const f32x16& t0, const f32x16& t1,
                    const char* __restrict__ gQ) {
#pragma unroll
    for (int s = 0; s < 4; ++s) {
      bf16x8 p = assemble((s < 2) ? t0 : t1, (s & 1) * 8, lh);
      bf16x8 q = *(const bf16x8*)(gQ + s * 1024);
      acc = __builtin_amdgcn_mfma_f32_32x32x16_bf16(p, q, acc, 0, 0, 0);
    }
  };
  // acc += plain (op1 @ X @ op2^T)[ti][tj]  (X = frag-major hat in LDS)
  auto sandP = [&](f32x16& acc, const char* X, int op1, int op2) {
    f32x16 t0 = {}, t1 = {};
    mmA(t0, X, 0, GF(op1, ti));
    mmA(t1, X, 1, GF(op1, ti));
    second(acc, t0, t1, GF(op2, tj));
  };
  // store hat-frags of plain C-tile into frag-major matrix dst (own slots)
  auto storeF = [&](char* dst, const f32x16& acc) {
#pragma unroll
    for (int sg = 0; sg < 2; ++sg) {
      bf16x8 f = assemble(acc, sg * 8, lh);
      *(bf16x8*)(dst + myslot + (sg << 10)) = f;
    }
  };
  // D = A + s*B on this wave's quarter (2KB) of a frag-major matrix
  auto axpyQ = [&](char* D, const char* A, float s, const char* Bm) {
#pragma unroll
    for (int j = 0; j < 8; ++j) {
      int off = 2048 * w + (j * 64 + l) * 4;
      unsigned a = *(const unsigned*)(A + off);
      unsigned bb = *(const unsigned*)(Bm + off);
      *(unsigned*)(D + off) = pk2(bflo(a) + s * bflo(bb), bfhi(a) + s * bfhi(bb));
    }
  };

  // ph1: stage rho0 -> hat frags in S1
  {
    const float* src = rho0g + b * 4096 + tid * 16;
    float vals[16];
#pragma unroll
    for (int q = 0; q < 4; ++q) {
      float4 f = *(const float4*)(src + q * 4);
      vals[q * 4 + 0] = f.x; vals[q * 4 + 1] = f.y;
      vals[q * 4 + 2] = f.z; vals[q * 4 + 3] = f.w;
    }
    int r = tid >> 2, c0 = (tid & 3) * 16;
    int base = ((r >> 4) << 10) + ((r & 7) * 2) + (((r >> 3) & 1) * 32) * 16;
#pragma unroll
    for (int u = 0; u < 16; ++u) {
      int c = c0 + u;
      *(unsigned short*)(S1 + ((c >> 5) << 12) + base + (c & 31) * 16) =
          bf16rne(vals[u]);
    }
  }
  __syncthreads();

  f32x16 outacc = {};

  // ph2: J0 = sum_k plain(L0k rho0 L0k^T) [reads S1] -> frags S2
  {
    f32x16 J = {};
#pragma unroll
    for (int k = 0; k < 4; ++k) sandP(J, S1, 3 + k, 3 + k);
    storeF(S2, J);
  }
  __syncthreads();

  // ph3: out += dt/6 * plain(U1,J0) [S2]; T = rho0 + 0.5dt*J0 -> S3
  {
    f32x16 a = {};
    sandP(a, S2, 0, 0);
    outacc += (dt / 6.f) * a;
    axpyQ(S3, S1, 0.5f * dt, S2);
  }
  __syncthreads();

  // ph4a: A=plain(U1,rho0): out+=A, P frags -> S2 (J0 dead);
  //       rho2 = plain(Um,T) [S3] -> S4
  {
    { f32x16 A = {}; sandP(A, S1, 0, 0); outacc += A; storeF(S2, A); }
    { f32x16 r2 = {}; sandP(r2, S3, 1, 1); storeF(S4, r2); }
  }
  // ph4b: S = plain(Um, rho0): read S1, BARRIER, then overwrite S1
  {
    f32x16 t0 = {}, t1 = {};
    mmA(t0, S1, 0, GF(1, ti));
    mmA(t1, S1, 1, GF(1, ti));
    __syncthreads();                    // all S1 reads (ph4a+4b) done
    f32x16 a = {};
    second(a, t0, t1, GF(1, tj));
    storeF(S1, a);
  }
  __syncthreads();

  // ph5: J2 [reads S4=rho2] -> S3 (T dead)
  {
    f32x16 J = {};
#pragma unroll
    for (int k = 0; k < 4; ++k) sandP(J, S4, 7 + k, 7 + k);
    storeF(S3, J);
  }
  __syncthreads();

  // ph6: rho3 = S + 0.5dt*J2 -> S4 (rho2 dead)
  axpyQ(S4, S1, 0.5f * dt, S3);
  __syncthreads();

  // ph7: J3 [reads S4] -> S1 (S dead)
  {
    f32x16 J = {};
#pragma unroll
    for (int k = 0; k < 4; ++k) sandP(J, S4, 7 + k, 7 + k);
    storeF(S1, J);
  }
  __syncthreads();

  // ph8: out += dt/3*(plain(Um1,J2)[S3] + plain(Um1,J3)[S1]);
  //      rho4 frags = P frags + dt*hat(plain(Um1,J3)) (rmw own S2 slots)
  {
    { f32x16 a = {}; sandP(a, S3, 2, 2); outacc += (dt / 3.f) * a; }
    {
      f32x16 g = {};
      sandP(g, S1, 2, 2);
      outacc += (dt / 3.f) * g;
#pragma unroll
      for (int sg = 0; sg < 2; ++sg) {
        bf16x8 F = assemble(g, sg * 8, lh);
        char* p = S2 + myslot + (sg << 10);
        bf16x8 old = *(const bf16x8*)p;
        bf16x8 nw;
#pragma unroll
        for (int i = 0; i < 8; ++i)
          nw[i] = (__bf16)((float)old[i] + dt * (float)F[i]);
        *(bf16x8*)p = nw;
      }
    }
  }
  __syncthreads();

  // ph9: out += dt/6 * jump(Ls1, rho4) [reads S2]
  {
    f32x16 J = {};
#pragma unroll
    for (int k = 0; k < 4; ++k) sandP(J, S2, 11 + k, 11 + k);
    outacc += (dt / 6.f) * J;
  }

  // store fp32 output tile (plain C layout)
  {
    float* op = outg + b * 4096 + (size_t)(ti * 32 + lh * 4) * 64 + tj * 32 + l31;
#pragma unroll
    for (int r = 0; r < 16; ++r) {
      int row = (r & 3) + 8 * (r >> 2);
      op[row * 64] = outacc[r];
    }
  }
}

extern "C" void kernel_launch(void* const* d_in, const int* in_sizes, int n_in,
                              void* d_out, int out_size, void* d_ws, size_t ws_size,
                              hipStream_t stream) {
  const float* rho0 = (const float*)d_in[0];
  const float* U1 = (const float*)d_in[1];
  const float* Um = (const float*)d_in[2];
  const float* Ls0 = (const float*)d_in[3];
  const float* Lsmid = (const float*)d_in[4];
  const float* Ls1 = (const float*)d_in[5];
  const float* dtp = (const float*)d_in[6];
  float* out = (float*)d_out;
  float* ws = (float*)d_ws;   // [0,16KB): Um1 fp32; [16KB,136KB): bf16 frags

  const int B = in_sizes[0] >> 12;

  kraus_invert<<<1, 256, 0, stream>>>(U1, Um, ws);
  kraus_prepack<<<15, 256, 0, stream>>>(U1, Um, Ls0, Lsmid, Ls1, ws);
  kraus_main<<<B, 256, 0, stream>>>(rho0, dtp, (const char*)d_ws + 16384, out);
}

// Round 11
// 283.641 us; speedup vs baseline: 1.4733x; 1.4733x over previous
//
#include <hip/hip_runtime.h>

// KrausRK4 via bf16 MFMA, r11: r10 structure (4 x 8KB frag-major LDS buffers,
// split-phase S-overwrite, 9 barriers) with __launch_bounds__(256,4) —
// r10's (256,5) capped VGPR at ~96 and spilled (840MB scratch writes).
// With ~64 VGPR + 32KB LDS the HW can still reach 5 blocks/CU.

typedef __attribute__((ext_vector_type(16))) float f32x16;
typedef __attribute__((ext_vector_type(8))) __bf16 bf16x8;

#define MATB 8192

__device__ __forceinline__ unsigned short bf16rne(float x) {
  unsigned u = __builtin_bit_cast(unsigned, x);
  return (unsigned short)((u + 0x7FFFu + ((u >> 16) & 1u)) >> 16);
}
__device__ __forceinline__ float bflo(unsigned u) {
  return __builtin_bit_cast(float, u << 16);
}
__device__ __forceinline__ float bfhi(unsigned u) {
  return __builtin_bit_cast(float, u & 0xFFFF0000u);
}
__device__ __forceinline__ unsigned pk2(float lo, float hi) {
  union { __bf16 h[2]; unsigned u; } r;
  r.h[0] = (__bf16)lo;
  r.h[1] = (__bf16)hi;
  return r.u;
}

union U4 { uint4 u; bf16x8 h; };

// Build step-s operand fragment (k = s*16 + lh*8 + i) from a C-tile.
__device__ __forceinline__ bf16x8 assemble(const f32x16& t, int b8, int lh) {
  unsigned u0 = pk2(t[b8 + 0], t[b8 + 1]);
  unsigned u1 = pk2(t[b8 + 2], t[b8 + 3]);
  unsigned w0 = pk2(t[b8 + 4], t[b8 + 5]);
  unsigned w1 = pk2(t[b8 + 6], t[b8 + 7]);
  unsigned z0 = lh ? u0 : w0;           // send what the partner needs
  unsigned z1 = lh ? u1 : w1;
  unsigned r0 = __shfl_xor(z0, 32);
  unsigned r1 = __shfl_xor(z1, 32);
  U4 r;
  r.u = make_uint4(lh ? r0 : u0, lh ? r1 : u1,
                   lh ? w0 : r0, lh ? w1 : r1);
  return r.h;
}

// ---------------- Um1 = U1 @ inv(Um), fp32 Gauss-Jordan, no pivot -----------
__global__ __launch_bounds__(256) void kraus_invert(
    const float* __restrict__ U1, const float* __restrict__ Um,
    float* __restrict__ Um1) {
  __shared__ float M[64][66];
  __shared__ float X[64][66];
  int tid = threadIdx.x;
#pragma unroll
  for (int it = 0; it < 16; ++it) {
    int idx = tid + 256 * it;
    int r = idx >> 6, c = idx & 63;
    M[r][c] = Um[idx];
    X[r][c] = (r == c) ? 1.0f : 0.0f;
  }
  __syncthreads();
  for (int k = 0; k < 64; ++k) {
    if (tid < 64) {
      float ip = 1.0f / M[k][k];
      M[k][tid] *= ip;
      X[k][tid] *= ip;
    }
    __syncthreads();
    int r = tid & 63, q = tid >> 6;
    float f = M[r][k];
    __syncthreads();
    if (r != k) {
#pragma unroll
      for (int cc = 0; cc < 16; ++cc) {
        int c = q * 16 + cc;
        M[r][c] -= f * M[k][c];
        X[r][c] -= f * X[k][c];
      }
    }
    __syncthreads();
  }
  for (int it = 0; it < 16; ++it) {
    int idx = tid + 256 * it;
    int i = idx >> 6, j = idx & 63;
    float s = 0.0f;
#pragma unroll 4
    for (int k = 0; k < 64; ++k) s += U1[i * 64 + k] * X[k][j];
    Um1[idx] = s;
  }
}

// ---------------- prepack: 15 operators -> bf16 fragment-major in ws --------
// op order: 0=U1 1=Um 2=Um1 3..6=Ls0 7..10=Lsmid 11..14=Ls1
__global__ __launch_bounds__(256) void kraus_prepack(
    const float* __restrict__ U1, const float* __restrict__ Um,
    const float* __restrict__ Ls0, const float* __restrict__ Lsmid,
    const float* __restrict__ Ls1, float* __restrict__ ws) {
  const float* Um1 = ws;
  unsigned short* dst = (unsigned short*)((char*)ws + 16384);
  int o = blockIdx.x;
  const float* s;
  if (o == 0) s = U1;
  else if (o == 1) s = Um;
  else if (o == 2) s = Um1;
  else if (o < 7) s = Ls0 + (o - 3) * 4096;
  else if (o < 11) s = Lsmid + (o - 7) * 4096;
  else s = Ls1 + (o - 11) * 4096;
  unsigned short* d = dst + o * 4096;
  int tid = threadIdx.x;
#pragma unroll
  for (int j = 0; j < 16; ++j) {
    int idx = tid + 256 * j;
    int f = idx >> 9, l = (idx >> 3) & 63, i = idx & 7;
    int t = f >> 2, ss = f & 3;
    int R = t * 32 + (l & 31);
    int C = ss * 16 + (l >> 5) * 8 + i;
    d[idx] = bf16rne(s[R * 64 + C]);
  }
}

// ---------------- main kernel: one block per batch item ---------------------
__global__ __launch_bounds__(256, 4) void kraus_main(
    const float* __restrict__ rho0g, const float* __restrict__ dtp,
    const char* __restrict__ gfrag, float* __restrict__ outg) {
  __shared__ __align__(16) char lds[4 * MATB];   // 32768 B
  char* S1 = lds;              // rho0 -> S -> J3
  char* S2 = S1 + MATB;        // J0 -> P -> rho4
  char* S3 = S2 + MATB;        // T -> J2
  char* S4 = S3 + MATB;        // rho2 -> rho3

  const int tid = threadIdx.x;
  const int l = tid & 63, w = tid >> 6;
  const int ti = w >> 1, tj = w & 1;
  const int l31 = l & 31, lh = l >> 5;
  const int fragoff = l * 16;
  const int myslot = ((tj * 4 + 2 * ti) << 10) + fragoff;
  const float dt = dtp[0];
  const size_t b = blockIdx.x;

  auto GF = [&](int op, int blk) {
    return gfrag + op * 8192 + blk * 4096 + l * 16;
  };
  auto mmA = [&](f32x16& acc, const char* X, int a, const char* __restrict__ gQ) {
#pragma unroll
    for (int s = 0; s < 4; ++s) {
      bf16x8 aa = *(const bf16x8*)(X + ((a * 4 + s) << 10) + fragoff);
      bf16x8 bb = *(const bf16x8*)(gQ + s * 1024);
      acc = __builtin_amdgcn_mfma_f32_32x32x16_bf16(aa, bb, acc, 0, 0, 0);
    }
  };
  auto second = [&](f32x16& acc, const f32x16& t0, const f32x16& t1,
                    const char* __restrict__ gQ) {
#pragma unroll
    for (int s = 0; s < 4; ++s) {
      bf16x8 p = assemble((s < 2) ? t0 : t1, (s & 1) * 8, lh);
      bf16x8 q = *(const bf16x8*)(gQ + s * 1024);
      acc = __builtin_amdgcn_mfma_f32_32x32x16_bf16(p, q, acc, 0, 0, 0);
    }
  };
  // acc += plain (op1 @ X @ op2^T)[ti][tj]  (X = frag-major hat in LDS)
  auto sandP = [&](f32x16& acc, const char* X, int op1, int op2) {
    f32x16 t0 = {}, t1 = {};
    mmA(t0, X, 0, GF(op1, ti));
    mmA(t1, X, 1, GF(op1, ti));
    second(acc, t0, t1, GF(op2, tj));
  };
  // store hat-frags of plain C-tile into frag-major matrix dst (own slots)
  auto storeF = [&](char* dst, const f32x16& acc) {
#pragma unroll
    for (int sg = 0; sg < 2; ++sg) {
      bf16x8 f = assemble(acc, sg * 8, lh);
      *(bf16x8*)(dst + myslot + (sg << 10)) = f;
    }
  };
  // D = A + s*B on this wave's quarter (2KB) of a frag-major matrix
  auto axpyQ = [&](char* D, const char* A, float s, const char* Bm) {
#pragma unroll
    for (int j = 0; j < 8; ++j) {
      int off = 2048 * w + (j * 64 + l) * 4;
      unsigned a = *(const unsigned*)(A + off);
      unsigned bb = *(const unsigned*)(Bm + off);
      *(unsigned*)(D + off) = pk2(bflo(a) + s * bflo(bb), bfhi(a) + s * bfhi(bb));
    }
  };

  // ph1: stage rho0 -> hat frags in S1
  {
    const float* src = rho0g + b * 4096 + tid * 16;
    float vals[16];
#pragma unroll
    for (int q = 0; q < 4; ++q) {
      float4 f = *(const float4*)(src + q * 4);
      vals[q * 4 + 0] = f.x; vals[q * 4 + 1] = f.y;
      vals[q * 4 + 2] = f.z; vals[q * 4 + 3] = f.w;
    }
    int r = tid >> 2, c0 = (tid & 3) * 16;
    int base = ((r >> 4) << 10) + ((r & 7) * 2) + (((r >> 3) & 1) * 32) * 16;
#pragma unroll
    for (int u = 0; u < 16; ++u) {
      int c = c0 + u;
      *(unsigned short*)(S1 + ((c >> 5) << 12) + base + (c & 31) * 16) =
          bf16rne(vals[u]);
    }
  }
  __syncthreads();

  f32x16 outacc = {};

  // ph2: J0 = sum_k plain(L0k rho0 L0k^T) [reads S1] -> frags S2
  {
    f32x16 J = {};
#pragma unroll
    for (int k = 0; k < 4; ++k) sandP(J, S1, 3 + k, 3 + k);
    storeF(S2, J);
  }
  __syncthreads();

  // ph3: out += dt/6 * plain(U1,J0) [S2]; T = rho0 + 0.5dt*J0 -> S3
  {
    f32x16 a = {};
    sandP(a, S2, 0, 0);
    outacc += (dt / 6.f) * a;
    axpyQ(S3, S1, 0.5f * dt, S2);
  }
  __syncthreads();

  // ph4a: A=plain(U1,rho0): out+=A, P frags -> S2 (J0 dead);
  //       rho2 = plain(Um,T) [S3] -> S4
  {
    { f32x16 A = {}; sandP(A, S1, 0, 0); outacc += A; storeF(S2, A); }
    { f32x16 r2 = {}; sandP(r2, S3, 1, 1); storeF(S4, r2); }
  }
  // ph4b: S = plain(Um, rho0): read S1, BARRIER, then overwrite S1
  {
    f32x16 t0 = {}, t1 = {};
    mmA(t0, S1, 0, GF(1, ti));
    mmA(t1, S1, 1, GF(1, ti));
    __syncthreads();                    // all S1 reads (ph4a+4b) done
    f32x16 a = {};
    second(a, t0, t1, GF(1, tj));
    storeF(S1, a);
  }
  __syncthreads();

  // ph5: J2 [reads S4=rho2] -> S3 (T dead)
  {
    f32x16 J = {};
#pragma unroll
    for (int k = 0; k < 4; ++k) sandP(J, S4, 7 + k, 7 + k);
    storeF(S3, J);
  }
  __syncthreads();

  // ph6: rho3 = S + 0.5dt*J2 -> S4 (rho2 dead)
  axpyQ(S4, S1, 0.5f * dt, S3);
  __syncthreads();

  // ph7: J3 [reads S4] -> S1 (S dead)
  {
    f32x16 J = {};
#pragma unroll
    for (int k = 0; k < 4; ++k) sandP(J, S4, 7 + k, 7 + k);
    storeF(S1, J);
  }
  __syncthreads();

  // ph8: out += dt/3*(plain(Um1,J2)[S3] + plain(Um1,J3)[S1]);
  //      rho4 frags = P frags + dt*hat(plain(Um1,J3)) (rmw own S2 slots)
  {
    { f32x16 a = {}; sandP(a, S3, 2, 2); outacc += (dt / 3.f) * a; }
    {
      f32x16 g = {};
      sandP(g, S1, 2, 2);
      outacc += (dt / 3.f) * g;
#pragma unroll
      for (int sg = 0; sg < 2; ++sg) {
        bf16x8 F = assemble(g, sg * 8, lh);
        char* p = S2 + myslot + (sg << 10);
        bf16x8 old = *(const bf16x8*)p;
        bf16x8 nw;
#pragma unroll
        for (int i = 0; i < 8; ++i)
          nw[i] = (__bf16)((float)old[i] + dt * (float)F[i]);
        *(bf16x8*)p = nw;
      }
    }
  }
  __syncthreads();

  // ph9: out += dt/6 * jump(Ls1, rho4) [reads S2]
  {
    f32x16 J = {};
#pragma unroll
    for (int k = 0; k < 4; ++k) sandP(J, S2, 11 + k, 11 + k);
    outacc += (dt / 6.f) * J;
  }

  // store fp32 output tile (plain C layout)
  {
    float* op = outg + b * 4096 + (size_t)(ti * 32 + lh * 4) * 64 + tj * 32 + l31;
#pragma unroll
    for (int r = 0; r < 16; ++r) {
      int row = (r & 3) + 8 * (r >> 2);
      op[row * 64] = outacc[r];
    }
  }
}

extern "C" void kernel_launch(void* const* d_in, const int* in_sizes, int n_in,
                              void* d_out, int out_size, void* d_ws, size_t ws_size,
                              hipStream_t stream) {
  const float* rho0 = (const float*)d_in[0];
  const float* U1 = (const float*)d_in[1];
  const float* Um = (const float*)d_in[2];
  const float* Ls0 = (const float*)d_in[3];
  const float* Lsmid = (const float*)d_in[4];
  const float* Ls1 = (const float*)d_in[5];
  const float* dtp = (const float*)d_in[6];
  float* out = (float*)d_out;
  float* ws = (float*)d_ws;   // [0,16KB): Um1 fp32; [16KB,136KB): bf16 frags

  const int B = in_sizes[0] >> 12;

  kraus_invert<<<1, 256, 0, stream>>>(U1, Um, ws);
  kraus_prepack<<<15, 256, 0, stream>>>(U1, Um, Ls0, Lsmid, Ls1, ws);
  kraus_main<<<B, 256, 0, stream>>>(rho0, dtp, (const char*)d_ws + 16384, out);
}

// Round 12
// 232.874 us; speedup vs baseline: 1.7945x; 1.2180x over previous
//
#include <hip/hip_runtime.h>

// KrausRK4 via bf16 MFMA, r12: r4 structure (best measured: 192.7us) +
// readfirstlane-uniform ti/tj (SALU addressing for global frag loads) +
// s_setprio around MFMA clusters (independent blocks -> T5 regime).
// LDS = 5 x 8KB swizzled matrices -> 4 blocks/CU, 58 barrier phases.
// phys(row, cbyte) = row*128 + (((cbyte>>4) ^ ((row>>3)&7))<<4) + (cbyte&15)

typedef __attribute__((ext_vector_type(16))) float f32x16;
typedef __attribute__((ext_vector_type(8))) __bf16 bf16x8;

#define MATB 8192

__device__ __forceinline__ unsigned short bf16rne(float x) {
  unsigned u = __builtin_bit_cast(unsigned, x);
  return (unsigned short)((u + 0x7FFFu + ((u >> 16) & 1u)) >> 16);
}
__device__ __forceinline__ float bflo(unsigned u) {
  return __builtin_bit_cast(float, u << 16);
}
__device__ __forceinline__ float bfhi(unsigned u) {
  return __builtin_bit_cast(float, u & 0xFFFF0000u);
}

// acc += P @ Q^T, P = operator frags (global), Q = LDS matrix rows (swizzled)
__device__ __forceinline__ void mm4_gl(f32x16& acc, const char* __restrict__ gP,
                                       const char* ldsQ, int vq, int lh) {
  __builtin_amdgcn_s_setprio(1);
#pragma unroll
  for (int s = 0; s < 4; ++s) {
    bf16x8 a = *(const bf16x8*)(gP + s * 1024);
    bf16x8 b = *(const bf16x8*)(ldsQ + (((2 * s + lh) ^ vq) << 4));
    acc = __builtin_amdgcn_mfma_f32_32x32x16_bf16(a, b, acc, 0, 0, 0);
  }
  __builtin_amdgcn_s_setprio(0);
}
// acc += P @ Q^T, P = LDS matrix rows (swizzled), Q = operator frags (global)
__device__ __forceinline__ void mm4_lg(f32x16& acc, const char* ldsP, int vp,
                                       int lh, const char* __restrict__ gQ) {
  __builtin_amdgcn_s_setprio(1);
#pragma unroll
  for (int s = 0; s < 4; ++s) {
    bf16x8 a = *(const bf16x8*)(ldsP + (((2 * s + lh) ^ vp) << 4));
    bf16x8 b = *(const bf16x8*)(gQ + s * 1024);
    acc = __builtin_amdgcn_mfma_f32_32x32x16_bf16(a, b, acc, 0, 0, 0);
  }
  __builtin_amdgcn_s_setprio(0);
}

// write 32x32 C-tile (row-major, swizzled): row = ti*32+4lh+(r&3)+8(r>>2)
__device__ __forceinline__ void wtile(char* base, int ti, int slotc, int coff,
                                      int lh, const f32x16& v) {
#pragma unroll
  for (int r = 0; r < 16; ++r) {
    int row = ti * 32 + 4 * lh + (r & 3) + 8 * (r >> 2);
    int ps = (slotc ^ ((4 * ti + (r >> 2)) & 7)) << 4;
    *(unsigned short*)(base + row * 128 + ps + coff) = bf16rne(v[r]);
  }
}
__device__ __forceinline__ void wtile_rmw(char* base, int ti, int slotc, int coff,
                                          int lh, const f32x16& v, float s) {
#pragma unroll
  for (int r = 0; r < 16; ++r) {
    int row = ti * 32 + 4 * lh + (r & 3) + 8 * (r >> 2);
    int ps = (slotc ^ ((4 * ti + (r >> 2)) & 7)) << 4;
    unsigned short* p = (unsigned short*)(base + row * 128 + ps + coff);
    float old = bflo((unsigned)*p);
    *p = bf16rne(old + s * v[r]);
  }
}

// D = A + s*B elementwise on raw swizzled dwords (2048 per matrix)
__device__ __forceinline__ void axpy(char* D, const char* A, float s,
                                     const char* B, int tid) {
#pragma unroll
  for (int j = 0; j < 8; ++j) {
    int off = (tid + 256 * j) * 4;
    unsigned a = *(const unsigned*)(A + off);
    unsigned b = *(const unsigned*)(B + off);
    float lo = bflo(a) + s * bflo(b);
    float hi = bfhi(a) + s * bfhi(b);
    *(unsigned*)(D + off) = (unsigned)bf16rne(lo) | ((unsigned)bf16rne(hi) << 16);
  }
}

// ---------------- Um1 = U1 @ inv(Um), fp32 Gauss-Jordan, no pivot -----------
__global__ __launch_bounds__(256) void kraus_invert(
    const float* __restrict__ U1, const float* __restrict__ Um,
    float* __restrict__ Um1) {
  __shared__ float M[64][66];
  __shared__ float X[64][66];
  int tid = threadIdx.x;
#pragma unroll
  for (int it = 0; it < 16; ++it) {
    int idx = tid + 256 * it;
    int r = idx >> 6, c = idx & 63;
    M[r][c] = Um[idx];
    X[r][c] = (r == c) ? 1.0f : 0.0f;
  }
  __syncthreads();
  for (int k = 0; k < 64; ++k) {
    if (tid < 64) {
      float ip = 1.0f / M[k][k];
      M[k][tid] *= ip;
      X[k][tid] *= ip;
    }
    __syncthreads();
    int r = tid & 63, q = tid >> 6;
    float f = M[r][k];
    __syncthreads();
    if (r != k) {
#pragma unroll
      for (int cc = 0; cc < 16; ++cc) {
        int c = q * 16 + cc;
        M[r][c] -= f * M[k][c];
        X[r][c] -= f * X[k][c];
      }
    }
    __syncthreads();
  }
  for (int it = 0; it < 16; ++it) {
    int idx = tid + 256 * it;
    int i = idx >> 6, j = idx & 63;
    float s = 0.0f;
#pragma unroll 4
    for (int k = 0; k < 64; ++k) s += U1[i * 64 + k] * X[k][j];
    Um1[idx] = s;
  }
}

// ---------------- prepack: 15 operators -> bf16 fragment-major in ws --------
// op order: 0=U1 1=Um 2=Um1 3..6=Ls0 7..10=Lsmid 11..14=Ls1
// frag elem: d[o*4096 + f*512 + l*8 + i] = M[t*32+(l&31)][s*16+(l>>5)*8+i], f=t*4+s
__global__ __launch_bounds__(256) void kraus_prepack(
    const float* __restrict__ U1, const float* __restrict__ Um,
    const float* __restrict__ Ls0, const float* __restrict__ Lsmid,
    const float* __restrict__ Ls1, float* __restrict__ ws) {
  const float* Um1 = ws;
  unsigned short* dst = (unsigned short*)((char*)ws + 16384);
  int o = blockIdx.x;
  const float* s;
  if (o == 0) s = U1;
  else if (o == 1) s = Um;
  else if (o == 2) s = Um1;
  else if (o < 7) s = Ls0 + (o - 3) * 4096;
  else if (o < 11) s = Lsmid + (o - 7) * 4096;
  else s = Ls1 + (o - 11) * 4096;
  unsigned short* d = dst + o * 4096;
  int tid = threadIdx.x;
#pragma unroll
  for (int j = 0; j < 16; ++j) {
    int idx = tid + 256 * j;
    int f = idx >> 9, l = (idx >> 3) & 63, i = idx & 7;
    int t = f >> 2, ss = f & 3;
    int R = t * 32 + (l & 31);
    int C = ss * 16 + (l >> 5) * 8 + i;
    d[idx] = bf16rne(s[R * 64 + C]);
  }
}

// ---------------- main kernel: one block per batch item ---------------------
__global__ __launch_bounds__(256, 4) void kraus_main(
    const float* __restrict__ rho0g, const float* __restrict__ dtp,
    const char* __restrict__ gfrag, float* __restrict__ outg) {
  __shared__ __align__(16) char lds[5 * MATB];   // 40960 B -> 4 blocks/CU
  char* B0 = lds;              // hat(rho0) -> hat(J2)
  char* B1 = B0 + MATB;        // hat(J0)->hat(T)->hat(rho2)->hat(rho3)->hat(JJ)
  char* B3 = B1 + MATB;        // hat(S) -> hat(J3)
  char* B4 = B3 + MATB;        // hat(P) -> hat(rho4)
  char* TMP = B4 + MATB;       // plain T intermediates

  const int tid = threadIdx.x;
  const int l = tid & 63, w = tid >> 6;
  // wave-uniform tile coords hoisted to SGPR (HK readfirstlane technique)
  const int ti = __builtin_amdgcn_readfirstlane(w >> 1);
  const int tj = __builtin_amdgcn_readfirstlane(w & 1);
  const int l31 = l & 31, lh = l >> 5;
  const int vA = (4 * ti + (l31 >> 3)) & 7;   // swizzle key, P-side rows
  const int vB = (4 * tj + (l31 >> 3)) & 7;   // swizzle key, Q-side rows
  const int rA = (ti * 32 + l31) * 128;
  const int rB = (tj * 32 + l31) * 128;
  const int slotc = 4 * tj + (l31 >> 3), coff = (l31 & 7) * 2;
  const float dt = dtp[0];
  const size_t b = blockIdx.x;
  const char* gA0 = gfrag + ti * 4096 + l * 16;   // + op*8192 : P-operand frags
  const char* gB0 = gfrag + tj * 4096 + l * 16;   // + op*8192 : Q-operand frags
#define GA(o) (gA0 + (o) * 8192)
#define GB(o) (gB0 + (o) * 8192)

  // stage hat(rho0): B0[c][r] = rho0[r][c], swizzled
  {
    const float* src = rho0g + b * 4096 + tid * 16;
    float vals[16];
#pragma unroll
    for (int q = 0; q < 4; ++q) {
      float4 f = *(const float4*)(src + q * 4);
      vals[q * 4 + 0] = f.x; vals[q * 4 + 1] = f.y;
      vals[q * 4 + 2] = f.z; vals[q * 4 + 3] = f.w;
    }
    int r = tid >> 2, c0 = (tid & 3) * 16;
    int sr = r >> 3, cr = (r & 7) * 2;
#pragma unroll
    for (int u = 0; u < 16; ++u) {
      int row = c0 + u;
      int ps = (sr ^ ((row >> 3) & 7)) << 4;
      *(unsigned short*)(B0 + row * 128 + ps + cr) = bf16rne(vals[u]);
    }
  }
  __syncthreads();

  f32x16 outacc = {};

  // J0 -> B1 (hat form), Ls0 = ops 3..6
  {
    f32x16 J = {};
    for (int k = 0; k < 4; ++k) {
      if (k) __syncthreads();
      f32x16 t = {};
      mm4_gl(t, GA(3 + k), B0 + rB, vB, lh);        // T = L @ rho0
      wtile(TMP, ti, slotc, coff, lh, t);
      __syncthreads();
      mm4_gl(J, GA(3 + k), TMP + rB, vB, lh);       // hat(J) += L @ T^T
    }
    __syncthreads();
    wtile(B1, ti, slotc, coff, lh, J);
  }
  __syncthreads();

  // out += dt/6 * sandwich(U1, J0)
  { f32x16 t = {}; mm4_gl(t, GA(0), B1 + rB, vB, lh); wtile(TMP, ti, slotc, coff, lh, t); }
  __syncthreads();
  { f32x16 s = {}; mm4_lg(s, TMP + rA, vA, lh, GB(0)); outacc += (dt / 6.f) * s; }
  __syncthreads();

  // P = sandwich(U1, rho0): out += P ; B4 = hat(P)
  { f32x16 t = {}; mm4_gl(t, GA(0), B0 + rB, vB, lh); wtile(TMP, ti, slotc, coff, lh, t); }
  __syncthreads();
  { f32x16 s = {}; mm4_lg(s, TMP + rA, vA, lh, GB(0)); outacc += s; }
  { f32x16 s = {}; mm4_gl(s, GA(0), TMP + rB, vB, lh); wtile(B4, ti, slotc, coff, lh, s); }

  // hat(T) = hat(rho0) + 0.5dt*hat(J0) -> B1
  axpy(B1, B0, 0.5f * dt, B1, tid);
  __syncthreads();

  // hat(rho2) = hat(sandwich(Um, T)) -> B1   (Um = op 1)
  { f32x16 t = {}; mm4_gl(t, GA(1), B1 + rB, vB, lh); wtile(TMP, ti, slotc, coff, lh, t); }
  __syncthreads();
  { f32x16 s = {}; mm4_gl(s, GA(1), TMP + rB, vB, lh); wtile(B1, ti, slotc, coff, lh, s); }
  __syncthreads();

  // hat(S) = hat(sandwich(Um, rho0)) -> B3
  { f32x16 t = {}; mm4_gl(t, GA(1), B0 + rB, vB, lh); wtile(TMP, ti, slotc, coff, lh, t); }
  __syncthreads();
  { f32x16 s = {}; mm4_gl(s, GA(1), TMP + rB, vB, lh); wtile(B3, ti, slotc, coff, lh, s); }
  __syncthreads();

  // J2 -> B0 (rho0 dead), Lsmid = ops 7..10
  {
    f32x16 J = {};
    for (int k = 0; k < 4; ++k) {
      if (k) __syncthreads();
      f32x16 t = {};
      mm4_gl(t, GA(7 + k), B1 + rB, vB, lh);        // L @ rho2
      wtile(TMP, ti, slotc, coff, lh, t);
      __syncthreads();
      mm4_gl(J, GA(7 + k), TMP + rB, vB, lh);
    }
    __syncthreads();
    wtile(B0, ti, slotc, coff, lh, J);
  }
  __syncthreads();
  // hat(rho3) = hat(S) + 0.5dt*hat(J2) -> B1
  axpy(B1, B3, 0.5f * dt, B0, tid);
  __syncthreads();

  // J3 -> B3 (S dead)
  {
    f32x16 J = {};
    for (int k = 0; k < 4; ++k) {
      if (k) __syncthreads();
      f32x16 t = {};
      mm4_gl(t, GA(7 + k), B1 + rB, vB, lh);        // L @ rho3
      wtile(TMP, ti, slotc, coff, lh, t);
      __syncthreads();
      mm4_gl(J, GA(7 + k), TMP + rB, vB, lh);
    }
    __syncthreads();
    wtile(B3, ti, slotc, coff, lh, J);
  }
  __syncthreads();
  // hat(JJ) = hat(J2) + hat(J3) -> B1
  axpy(B1, B0, 1.0f, B3, tid);
  __syncthreads();

  // out += dt/3 * sandwich(Um1, JJ)   (Um1 = op 2)
  { f32x16 t = {}; mm4_gl(t, GA(2), B1 + rB, vB, lh); wtile(TMP, ti, slotc, coff, lh, t); }
  __syncthreads();
  { f32x16 s = {}; mm4_lg(s, TMP + rA, vA, lh, GB(2)); outacc += (dt / 3.f) * s; }
  __syncthreads();

  // hat(rho4) = hat(P) + dt * hat(sandwich(Um1, J3)) -> B4
  { f32x16 t = {}; mm4_gl(t, GA(2), B3 + rB, vB, lh); wtile(TMP, ti, slotc, coff, lh, t); }
  __syncthreads();
  { f32x16 s = {}; mm4_gl(s, GA(2), TMP + rB, vB, lh); wtile_rmw(B4, ti, slotc, coff, lh, s, dt); }
  __syncthreads();

  // out += dt/6 * jump(Ls1, rho4), plain form; Ls1 = ops 11..14
  {
    f32x16 J = {};
    for (int k = 0; k < 4; ++k) {
      if (k) __syncthreads();
      f32x16 t = {};
      mm4_gl(t, GA(11 + k), B4 + rB, vB, lh);       // L @ rho4
      wtile(TMP, ti, slotc, coff, lh, t);
      __syncthreads();
      mm4_lg(J, TMP + rA, vA, lh, GB(11 + k));      // plain: T @ L^T
    }
    outacc += (dt / 6.f) * J;
  }

  // store fp32 output tile
  {
    float* op = outg + b * 4096 + (size_t)(ti * 32 + lh * 4) * 64 + tj * 32 + l31;
#pragma unroll
    for (int r = 0; r < 16; ++r) {
      int row = (r & 3) + 8 * (r >> 2);
      op[row * 64] = outacc[r];
    }
  }
#undef GA
#undef GB
}

extern "C" void kernel_launch(void* const* d_in, const int* in_sizes, int n_in,
                              void* d_out, int out_size, void* d_ws, size_t ws_size,
                              hipStream_t stream) {
  const float* rho0 = (const float*)d_in[0];
  const float* U1 = (const float*)d_in[1];
  const float* Um = (const float*)d_in[2];
  const float* Ls0 = (const float*)d_in[3];
  const float* Lsmid = (const float*)d_in[4];
  const float* Ls1 = (const float*)d_in[5];
  const float* dtp = (const float*)d_in[6];
  float* out = (float*)d_out;
  float* ws = (float*)d_ws;   // [0,16KB): Um1 fp32; [16KB,136KB): bf16 frags

  const int B = in_sizes[0] >> 12;

  kraus_invert<<<1, 256, 0, stream>>>(U1, Um, ws);
  kraus_prepack<<<15, 256, 0, stream>>>(U1, Um, Ls0, Lsmid, Ls1, ws);
  kraus_main<<<B, 256, 0, stream>>>(rho0, dtp, (const char*)d_ws + 16384, out);
}